// Round 1
// 905.431 us; speedup vs baseline: 1.0403x; 1.0403x over previous
//
#include <hip/hip_runtime.h>

// QuantLinear: y[t,o] = (sum_k x[t,k] * (q[o,k]-8)) * scale[o] + bias[o]
// Scale factored out of K-reduction -> bf16 MFMA GEMM on (q-8), epilogue scale/bias.
// This round: 256x256x64 8-phase pipelined GEMM (guide §5 template):
//   - 8 waves (2Mx4N), 512 threads, per-wave 128x64 output, acc[8][4] f32x4
//   - LDS 128 KiB: 2 dbuf x (A 256x64 + B 256x64) bf16
//   - st_16x32 swizzle via pre-swizzled global source + swizzled ds_read lane offset
//   - 4 phases per K-tile: quadrants (m0-3/m4-7 x n0-1/n2-3) over K=64;
//     all LDS reads of a tile done by phase 2 -> phase 3/4 may stage into same buffer
//   - 1 half-tile (2x global_load_lds width-16) staged per phase; vmcnt(4) once
//     per K-tile (counted, never 0 until the final pair); s_setprio around MFMA
//   - bijective XCD swizzle over the 896-block grid (896 % 8 == 0)

#define AS1 __attribute__((address_space(1)))
#define AS3 __attribute__((address_space(3)))

typedef __attribute__((ext_vector_type(8))) short short8;
typedef __attribute__((ext_vector_type(4))) float f32x4;

static constexpr int IN_F   = 4096;    // K
static constexpr int OUT_F  = 14336;   // N
static constexpr int TOKENS = 4096;    // M

// ---------------- fused conversion kernel ----------------

__device__ __forceinline__ unsigned short bf16_rne(float f) {
    unsigned int u = __float_as_uint(f);
    u += 0x7fffu + ((u >> 16) & 1u);
    return (unsigned short)(u >> 16);
}

__global__ void convert_kernel(const int4* __restrict__ q, ushort4* __restrict__ wb,
                               const float4* __restrict__ x, ushort4* __restrict__ xb) {
    constexpr size_t NW = (size_t)OUT_F * IN_F / 4;   // 14,680,064 int4-groups
    size_t i = (size_t)blockIdx.x * blockDim.x + threadIdx.x;
    if (i < NW) {
        int4 v = q[i];
        ushort4 r;  // small ints exact in bf16: truncate fp32 bits
        r.x = (unsigned short)(__float_as_uint((float)(v.x - 8)) >> 16);
        r.y = (unsigned short)(__float_as_uint((float)(v.y - 8)) >> 16);
        r.z = (unsigned short)(__float_as_uint((float)(v.z - 8)) >> 16);
        r.w = (unsigned short)(__float_as_uint((float)(v.w - 8)) >> 16);
        wb[i] = r;
    } else {
        size_t j = i - NW;
        float4 v = x[j];
        ushort4 r;
        r.x = bf16_rne(v.x); r.y = bf16_rne(v.y);
        r.z = bf16_rne(v.z); r.w = bf16_rne(v.w);
        xb[j] = r;
    }
}

// ---------------- 256x256x64 8-phase GEMM: C = A * B^T ----------------

#define STAGE(T_, Q_, MATP_)                                                               \
    do {                                                                                   \
        const unsigned short* g_ = ((Q_) < 2 ? gA : gB) + ((Q_) & 1) * (size_t)(128 * K)   \
                                   + (size_t)(T_) * BK;                                    \
        unsigned short* l_ = (MATP_) + ((Q_) & 1) * HS + tid * 8;                          \
        __builtin_amdgcn_global_load_lds((const AS1 void*)g_, (AS3 void*)l_, 16, 0, 0);    \
        __builtin_amdgcn_global_load_lds((const AS1 void*)(g_ + (size_t)64 * K),           \
                                         (AS3 void*)(l_ + 4096), 16, 0, 0);                \
    } while (0)

#define BAR()                                                                              \
    do {                                                                                   \
        asm volatile("" ::: "memory");                                                     \
        __builtin_amdgcn_s_barrier();                                                      \
        asm volatile("" ::: "memory");                                                     \
    } while (0)

#define MFMA_QUAD(M0_, N0_)                                                                \
    __builtin_amdgcn_s_setprio(1);                                                         \
    _Pragma("unroll") for (int s_ = 0; s_ < 2; ++s_)                                       \
        _Pragma("unroll") for (int m_ = 0; m_ < 4; ++m_)                                   \
            _Pragma("unroll") for (int n_ = 0; n_ < 2; ++n_)                               \
                acc[(M0_) + m_][(N0_) + n_] = __builtin_amdgcn_mfma_f32_16x16x32_bf16(     \
                    af[(M0_) + m_][s_], bf[(N0_) + n_][s_],                                \
                    acc[(M0_) + m_][(N0_) + n_], 0, 0, 0);                                 \
    __builtin_amdgcn_s_setprio(0);

// One K-tile = 4 phases. TA_/TB_: current buffers. NXA_: A of SAME buffer
// (receives tile T+2, safe from phase 3: all reads of tile T finish in phase 2).
// NXB_: B of OTHER buffer (receives tile T+1).
#define KTILE(T_, TA_, TB_, NXA_, NXB_)                                                    \
    do {                                                                                   \
        /* --- phase 1: read A m0-3 + B n0-1 (both k-steps); quad (m0-3 x n0-1) --- */     \
        _Pragma("unroll") for (int m_ = 0; m_ < 4; ++m_) {                                 \
            af[m_][0] = *(const short8*)((TA_) + aOff + m_ * 1024);                        \
            af[m_][1] = *(const short8*)((TA_) + aOff + m_ * 1024 + 32);                   \
        }                                                                                  \
        _Pragma("unroll") for (int n_ = 0; n_ < 2; ++n_) {                                 \
            bf[n_][0] = *(const short8*)((TB_) + bOff + n_ * 1024);                        \
            bf[n_][1] = *(const short8*)((TB_) + bOff + n_ * 1024 + 32);                   \
        }                                                                                  \
        if ((T_) + 1 < NT) STAGE((T_) + 1, 2, NXB_);                                       \
        BAR();                                                                             \
        asm volatile("s_waitcnt lgkmcnt(0)" ::: "memory");                                 \
        MFMA_QUAD(0, 0)                                                                    \
        BAR();                                                                             \
        /* --- phase 2: read A m4-7 + B n2-3; quad (m4-7 x n0-1) --- */                    \
        _Pragma("unroll") for (int m_ = 0; m_ < 4; ++m_) {                                 \
            af[4 + m_][0] = *(const short8*)((TA_) + aOff + (4 + m_) * 1024);              \
            af[4 + m_][1] = *(const short8*)((TA_) + aOff + (4 + m_) * 1024 + 32);         \
        }                                                                                  \
        _Pragma("unroll") for (int n_ = 0; n_ < 2; ++n_) {                                 \
            bf[2 + n_][0] = *(const short8*)((TB_) + bOff + (2 + n_) * 1024);              \
            bf[2 + n_][1] = *(const short8*)((TB_) + bOff + (2 + n_) * 1024 + 32);         \
        }                                                                                  \
        if ((T_) + 1 < NT) STAGE((T_) + 1, 3, NXB_);                                       \
        BAR();                                                                             \
        asm volatile("s_waitcnt lgkmcnt(0)" ::: "memory");                                 \
        MFMA_QUAD(4, 0)                                                                    \
        BAR();                                                                             \
        /* --- phase 3: no reads; quad (m0-3 x n2-3) --- */                                \
        if ((T_) + 2 < NT) STAGE((T_) + 2, 0, NXA_);                                       \
        BAR();                                                                             \
        MFMA_QUAD(0, 2)                                                                    \
        BAR();                                                                             \
        /* --- phase 4: no reads; quad (m4-7 x n2-3); counted vmcnt --- */                 \
        if ((T_) + 2 < NT) STAGE((T_) + 2, 1, NXA_);                                       \
        BAR();                                                                             \
        MFMA_QUAD(4, 2)                                                                    \
        if ((T_) + 2 < NT) {                                                               \
            asm volatile("s_waitcnt vmcnt(4)" ::: "memory");                               \
        } else {                                                                           \
            asm volatile("s_waitcnt vmcnt(0)" ::: "memory");                               \
        }                                                                                  \
        BAR();                                                                             \
    } while (0)

__global__ __launch_bounds__(512, 2)
void gemm256_kernel(const unsigned short* __restrict__ A,   // bf16 [M,K]
                    const unsigned short* __restrict__ B,   // bf16 [N,K]
                    const float* __restrict__ scale,        // [N]
                    const float* __restrict__ bias,         // [N]
                    float* __restrict__ C) {                // [M,N]
    constexpr int K  = IN_F;
    constexpr int N  = OUT_F;
    constexpr int BK = 64;
    constexpr int NT = K / BK;        // 64 K-tiles
    constexpr int TS = 256 * BK;      // shorts per tile (16384 = 32 KiB)
    constexpr int HS = TS / 2;        // shorts per 128-row half

    __shared__ unsigned short sm[2][2][TS];   // [buf][A|B][256*64] = 128 KiB

    const int tid  = threadIdx.x;
    const int lane = tid & 63;
    const int wave = tid >> 6;
    const int l16  = lane & 15;
    const int lq   = lane >> 4;
    const int wr   = wave >> 2;       // 0..1  (M position)
    const int wc   = wave & 3;        // 0..3  (N position)

    // bijective XCD swizzle: 896 tiles, each XCD gets 112 contiguous logical
    // tiles = 2 full M-rows -> A panel (4 MB) fits that XCD's L2.
    const int bid   = blockIdx.y * 56 + blockIdx.x;
    const int swz   = (bid & 7) * 112 + (bid >> 3);
    const int nBase = (swz % 56) * 256;
    const int mBase = (swz / 56) * 256;

    // staging: LDS chunk c (16B) must hold global chunk c ^ ((c>>5 & 1) << 1)
    // (st_16x32: byte ^= ((byte>>9)&1)<<5, involution on 16B chunks).
    const int cs   = tid ^ (((tid >> 5) & 1) << 1);
    const int srow = cs >> 3;          // 0..63
    const int scol = (cs & 7) * 8;     // shorts within row
    const unsigned short* gA = A + (size_t)(mBase + srow) * K + scol;
    const unsigned short* gB = B + (size_t)(nBase + srow) * K + scol;

    // swizzled reader: lane (l16,lq) reads k-chunk position lq ^ ((l16&4)>>1)
    const int klane = lq ^ ((l16 >> 1) & 2);
    const int aOff  = (wr * 128 + l16) * 64 + klane * 8;
    const int bOff  = (wc * 64  + l16) * 64 + klane * 8;

    f32x4  acc[8][4] = {};
    short8 af[8][2];
    short8 bf[4][2];

    unsigned short* smA0 = &sm[0][0][0];
    unsigned short* smB0 = &sm[0][1][0];
    unsigned short* smA1 = &sm[1][0][0];
    unsigned short* smB1 = &sm[1][1][0];

    // prologue: tile0 {A0,A1,B0,B1} + tile1 {A0,A1}; drain tile0, keep 4 in flight
    STAGE(0, 0, smA0); STAGE(0, 1, smA0); STAGE(0, 2, smB0); STAGE(0, 3, smB0);
    STAGE(1, 0, smA1); STAGE(1, 1, smA1);
    asm volatile("s_waitcnt vmcnt(4)" ::: "memory");
    BAR();

    for (int t = 0; t < NT; t += 2) {
        KTILE(t,     smA0, smB0, smA0, smB1);
        KTILE(t + 1, smA1, smB1, smA1, smB0);
    }

    // epilogue: C/D layout col = lane&15 (n side), row = (lane>>4)*4 + reg (m side)
#pragma unroll
    for (int n = 0; n < 4; ++n) {
        const int col  = nBase + wc * 64 + n * 16 + l16;
        const float s  = scale[col];
        const float bb = bias[col];
#pragma unroll
        for (int m = 0; m < 8; ++m) {
            const int row0 = mBase + wr * 128 + m * 16 + lq * 4;
            float* cp = C + (size_t)row0 * N + col;
#pragma unroll
            for (int r = 0; r < 4; ++r)
                cp[(size_t)r * N] = acc[m][n][r] * s + bb;
        }
    }
}

// ---------------- launch ----------------

extern "C" void kernel_launch(void* const* d_in, const int* in_sizes, int n_in,
                              void* d_out, int out_size, void* d_ws, size_t ws_size,
                              hipStream_t stream) {
    const float* x      = (const float*)d_in[0];  // [2,2048,4096] fp32
    const int*   wq     = (const int*)d_in[1];    // [14336,4096] int32 in [0,16)
    const float* wscale = (const float*)d_in[2];  // [14336,1]
    const float* wbias  = (const float*)d_in[3];  // [14336]
    float* out = (float*)d_out;                   // [2,2048,14336] fp32

    unsigned short* wbf = (unsigned short*)d_ws;                    // 117.4 MB
    unsigned short* xbf = wbf + (size_t)OUT_F * IN_F;               // +33.6 MB

    // fused: 57,344 w-blocks + 16,384 x-blocks
    convert_kernel<<<73728, 256, 0, stream>>>((const int4*)wq, (ushort4*)wbf,
                                              (const float4*)x, (ushort4*)xbf);

    gemm256_kernel<<<dim3(56, 16), 512, 0, stream>>>(xbf, wbf, wscale, wbias, out);
}